// Round 5
// baseline (165.979 us; speedup 1.0000x reference)
//
#include <hip/hip_runtime.h>
#include <hip/hip_bf16.h>
#include <hip/hip_fp16.h>

// Problem constants
#define NXv 128
#define NYv 128
#define NZv 8
#define NVOX (NXv * NYv * NZv)   // 131072
#define NV 6
#define NC 64
#define HFv 116
#define WFv 200
#define PLANE (HFv * WFv)        // 23200

#define FT_BYTES ((size_t)NV * PLANE * NC * 2)   // 17,817,600 (bf16 channels-last)

// INSTRUMENTATION ROUND: idempotent repeat factors to lift both kernels above
// the ~44us fill cutoff in the top-5 rocprof table. Remove next round.
#define K1_REP 8
#define K2_REP 4

// ---- helpers ---------------------------------------------------------------
__device__ inline unsigned int f2bf(float f) {   // f32 -> bf16 bits, RNE
  unsigned int x = __float_as_uint(f);
  unsigned int r = x + 0x7fffu + ((x >> 16) & 1u);
  return (r >> 16) & 0xffffu;
}
__device__ inline float bf_lo(unsigned int q) { return __uint_as_float(q << 16); }
__device__ inline float bf_hi(unsigned int q) { return __uint_as_float(q & 0xffff0000u); }

__device__ inline unsigned short f2h_bits(float f) {
  __half h = __float2half(f);
  return *reinterpret_cast<unsigned short*>(&h);
}
__device__ inline float h_bits2f(unsigned short u) {
  __half_raw r; r.x = u;
  __half h = *reinterpret_cast<__half*>(&r);
  return __half2float(h);
}

// ---------------------------------------------------------------------------
// K1: Transpose+convert [V][C][PLANE] f32 -> [V][PLANE][C] bf16 (packed).
// Instrumented: x K1_REP idempotent repeats.
// ---------------------------------------------------------------------------
__global__ __launch_bounds__(256) void transpose_feat_bf16(
    const float* __restrict__ in, unsigned int* __restrict__ out32) {
  __shared__ float tile[64][65];                 // [pixel][channel]
  const int v  = blockIdx.y;
  const int p0 = blockIdx.x * 64;
  const float* src = in + (size_t)v * NC * PLANE;
  unsigned int* dst = out32 + (size_t)v * PLANE * (NC / 2);
  const int t = threadIdx.x;

  for (int rep = 0; rep < K1_REP; ++rep) {
#pragma unroll
    for (int i = 0; i < 4; ++i) {
      const int idx = i * 256 + t;
      const int c  = idx >> 4;
      const int p4 = idx & 15;
      const int pp = p0 + p4 * 4;
      if (pp < PLANE) {                          // PLANE%4==0 -> full float4 ok
        const float4 f = *(const float4*)(src + (size_t)c * PLANE + pp);
        tile[p4 * 4 + 0][c] = f.x;
        tile[p4 * 4 + 1][c] = f.y;
        tile[p4 * 4 + 2][c] = f.z;
        tile[p4 * 4 + 3][c] = f.w;
      }
    }
    __syncthreads();

#pragma unroll
    for (int i = 0; i < 2; ++i) {
      const int idx = i * 256 + t;
      const int p   = idx >> 3;
      const int c8  = idx & 7;
      const int pp  = p0 + p;
      if (pp < PLANE) {
        uint4 w;
        w.x = f2bf(tile[p][c8 * 8 + 0]) | (f2bf(tile[p][c8 * 8 + 1]) << 16);
        w.y = f2bf(tile[p][c8 * 8 + 2]) | (f2bf(tile[p][c8 * 8 + 3]) << 16);
        w.z = f2bf(tile[p][c8 * 8 + 4]) | (f2bf(tile[p][c8 * 8 + 5]) << 16);
        w.w = f2bf(tile[p][c8 * 8 + 6]) | (f2bf(tile[p][c8 * 8 + 7]) << 16);
        *(uint4*)(dst + (size_t)pp * 32 + c8 * 4) = w;
      }
    }
    __syncthreads();                             // tile reuse across reps
  }
}

// ---------------------------------------------------------------------------
// K2: Fused projection + gather + coalesced store (compacted views).
// rec layout (per valid (slot,view)):
//   rec.x = p00 | (v&1)<<15 | p10<<16 | ((v>>1)&1)<<31
//   rec.y = p01 | ((v>>2)&1)<<15 | p11<<16
//   rec.z = f16(w00) | f16(w10)<<16
//   rec.w = f16(w01) | f16(w11)<<16
// Instrumented: x K2_REP idempotent repeats (same values rewritten).
// ---------------------------------------------------------------------------
__global__ __launch_bounds__(256, 4) void gather_fused(
    const uint4* __restrict__ feat4,    // [V*PLANE][8] uint4 (64 bf16 ch)
    const float* __restrict__ points,
    const float* __restrict__ proj,
    float* __restrict__ out) {
  __shared__ unsigned short tile_h[64][66];   // f16 staging, 8.4KB
  __shared__ uint4 pdl[64 * NV];              // 6KB
  __shared__ int   cntl[64];
  __shared__ float invl[64];
  __shared__ float projl[96];

  // spatial swizzle: XCD (~bi&7) owns two 32ix x 32iy squares
  const int bi   = blockIdx.x;
  const int xcd  = bi & 7;
  const int r    = bi >> 3;
  const int tid  = xcd * 2 + (r >> 7);
  const int q    = r & 127;
  const int ix   = (tid & 3) * 32 + (q & 31);
  const int iyg  = (tid >> 2) * 4 + (q >> 5);
  const int iy0g = iyg * 8;

  const int t    = threadIdx.x;
  const int lane = t & 63;
  const int wave = t >> 6;

  if (t < 96) projl[t] = proj[t];

  for (int rep = 0; rep < K2_REP; ++rep) {
    __syncthreads();   // projl ready (rep 0); tile_h reads done (reps >= 1)

    // ---- Phase A: one thread per slot, views in registers, zero-pad to NV ----
    if (t < 64) {
      const int slot = t;
      const int j    = slot >> 3;
      const int iz   = slot & 7;
      const int n    = iz * (NXv * NYv) + (iy0g + j) * NXv + ix;

      const float x = points[n * 3 + 0];
      const float y = points[n * 3 + 1];
      const float z = points[n * 3 + 2];

      int cnt = 0;
#pragma unroll
      for (int v = 0; v < NV; ++v) {
        const float* M = projl + v * 16;
        const float cx = M[0] * x + M[1] * y + M[2]  * z + M[3];
        const float cy = M[4] * x + M[5] * y + M[6]  * z + M[7];
        const float cz = M[8] * x + M[9] * y + M[10] * z + M[11];

        const float dz = (fabsf(cz) > 1e-6f) ? cz : 1e-6f;
        const float u  = cx / dz;
        const float vv = cy / dz;

        const bool valid = (cz > 0.0f) && (u > 0.0f) && (u < 1600.0f) &&
                           (vv > 0.0f) && (vv < 928.0f);
        if (valid) {
          const float px = u  / 1600.0f * 200.0f - 0.5f;
          const float py = vv / 928.0f  * 116.0f - 0.5f;
          const float fx0 = floorf(px);
          const float fy0 = floorf(py);
          const float wx1 = px - fx0;
          const float wy1 = py - fy0;
          const float wx0 = 1.0f - wx1;
          const float wy0 = 1.0f - wy1;
          const int ix0 = (int)fx0;
          const int iy0 = (int)fy0;

          // per-tap in-bounds masks (reference semantics)
          const bool bx0 = (ix0 >= 0) && (ix0 < WFv);
          const bool bx1 = (ix0 + 1 >= 0) && (ix0 + 1 < WFv);
          const bool by0 = (iy0 >= 0) && (iy0 < HFv);
          const bool by1 = (iy0 + 1 >= 0) && (iy0 + 1 < HFv);

          // per-tap independently clamped coords (reference semantics)
          const int xc0 = min(max(ix0, 0), WFv - 1);
          const int xc1 = min(max(ix0 + 1, 0), WFv - 1);
          const int yc0 = min(max(iy0, 0), HFv - 1);
          const int yc1 = min(max(iy0 + 1, 0), HFv - 1);
          const unsigned int p00 = (unsigned int)(yc0 * WFv + xc0);
          const unsigned int p10 = (unsigned int)(yc0 * WFv + xc1);
          const unsigned int p01 = (unsigned int)(yc1 * WFv + xc0);
          const unsigned int p11 = (unsigned int)(yc1 * WFv + xc1);
          const unsigned int uv = (unsigned int)v;

          uint4 rec;
          rec.x = p00 | ((uv & 1u) << 15) | (p10 << 16) | (((uv >> 1) & 1u) << 31);
          rec.y = p01 | (((uv >> 2) & 1u) << 15) | (p11 << 16);
          rec.z = (unsigned int)f2h_bits((bx0 && by0) ? wx0 * wy0 : 0.0f) |
                  ((unsigned int)f2h_bits((bx1 && by0) ? wx1 * wy0 : 0.0f) << 16);
          rec.w = (unsigned int)f2h_bits((bx0 && by1) ? wx0 * wy1 : 0.0f) |
                  ((unsigned int)f2h_bits((bx1 && by1) ? wx1 * wy1 : 0.0f) << 16);
          pdl[slot * NV + cnt] = rec;
          ++cnt;
        }
      }
      cntl[slot] = cnt;
      invl[slot] = (cnt > 0) ? 1.0f / (float)cnt : 0.0f;
      // zero-weight padding: Phase B reads these branchlessly; w=0 => inert
      const uint4 zrec = {0u, 0u, 0u, 0u};
      for (int k = cnt; k < NV; ++k) pdl[slot * NV + k] = zrec;
    }
    __syncthreads();

    // ---- Phase B: branchless taps over padded record lists ----
    const int pg = lane >> 3;    // point within group of 8
    const int ch = lane & 7;     // uint4 chunk (8 channels)

#pragma unroll
    for (int it = 0; it < 2; ++it) {
      const int sl = wave * 16 + it * 8 + pg;
      int km = cntl[sl];
      km = max(km, __shfl_xor(km, 8));
      km = max(km, __shfl_xor(km, 16));
      km = max(km, __shfl_xor(km, 32));   // wave-uniform max over the 8 points

      float acc[8];
#pragma unroll
      for (int j2 = 0; j2 < 8; ++j2) acc[j2] = 0.0f;

      const int base = sl * NV;
      for (int k = 0; k < km; ++k) {
        const uint4 cur = pdl[base + k];
        const unsigned int p00 = cur.x & 0x7fffu;
        const unsigned int p10 = (cur.x >> 16) & 0x7fffu;
        const unsigned int p01 = cur.y & 0x7fffu;
        const unsigned int p11 = (cur.y >> 16) & 0x7fffu;
        const unsigned int v = ((cur.x >> 15) & 1u) | (((cur.x >> 31) & 1u) << 1) |
                               (((cur.y >> 15) & 1u) << 2);
        const float w0 = h_bits2f((unsigned short)(cur.z & 0xffffu));
        const float w1 = h_bits2f((unsigned short)(cur.z >> 16));
        const float w2 = h_bits2f((unsigned short)(cur.w & 0xffffu));
        const float w3 = h_bits2f((unsigned short)(cur.w >> 16));

        const uint4* fb = feat4 + (size_t)v * PLANE * 8 + ch;
        const uint4 q0 = fb[(size_t)p00 * 8];
        const uint4 q1 = fb[(size_t)p10 * 8];
        const uint4 q2 = fb[(size_t)p01 * 8];
        const uint4 q3 = fb[(size_t)p11 * 8];

        acc[0] = fmaf(w0, bf_lo(q0.x), acc[0]); acc[1] = fmaf(w0, bf_hi(q0.x), acc[1]);
        acc[2] = fmaf(w0, bf_lo(q0.y), acc[2]); acc[3] = fmaf(w0, bf_hi(q0.y), acc[3]);
        acc[4] = fmaf(w0, bf_lo(q0.z), acc[4]); acc[5] = fmaf(w0, bf_hi(q0.z), acc[5]);
        acc[6] = fmaf(w0, bf_lo(q0.w), acc[6]); acc[7] = fmaf(w0, bf_hi(q0.w), acc[7]);

        acc[0] = fmaf(w1, bf_lo(q1.x), acc[0]); acc[1] = fmaf(w1, bf_hi(q1.x), acc[1]);
        acc[2] = fmaf(w1, bf_lo(q1.y), acc[2]); acc[3] = fmaf(w1, bf_hi(q1.y), acc[3]);
        acc[4] = fmaf(w1, bf_lo(q1.z), acc[4]); acc[5] = fmaf(w1, bf_hi(q1.z), acc[5]);
        acc[6] = fmaf(w1, bf_lo(q1.w), acc[6]); acc[7] = fmaf(w1, bf_hi(q1.w), acc[7]);

        acc[0] = fmaf(w2, bf_lo(q2.x), acc[0]); acc[1] = fmaf(w2, bf_hi(q2.x), acc[1]);
        acc[2] = fmaf(w2, bf_lo(q2.y), acc[2]); acc[3] = fmaf(w2, bf_hi(q2.y), acc[3]);
        acc[4] = fmaf(w2, bf_lo(q2.z), acc[4]); acc[5] = fmaf(w2, bf_hi(q2.z), acc[5]);
        acc[6] = fmaf(w2, bf_lo(q2.w), acc[6]); acc[7] = fmaf(w2, bf_hi(q2.w), acc[7]);

        acc[0] = fmaf(w3, bf_lo(q3.x), acc[0]); acc[1] = fmaf(w3, bf_hi(q3.x), acc[1]);
        acc[2] = fmaf(w3, bf_lo(q3.y), acc[2]); acc[3] = fmaf(w3, bf_hi(q3.y), acc[3]);
        acc[4] = fmaf(w3, bf_lo(q3.z), acc[4]); acc[5] = fmaf(w3, bf_hi(q3.z), acc[5]);
        acc[6] = fmaf(w3, bf_lo(q3.w), acc[6]); acc[7] = fmaf(w3, bf_hi(q3.w), acc[7]);
      }

      const float inv = invl[sl];
#pragma unroll
      for (int j2 = 0; j2 < 4; ++j2) {
        const unsigned int pk =
            (unsigned int)f2h_bits(acc[j2 * 2 + 0] * inv) |
            ((unsigned int)f2h_bits(acc[j2 * 2 + 1] * inv) << 16);
        *(unsigned int*)&tile_h[sl][ch * 8 + j2 * 2] = pk;
      }
    }

    __syncthreads();

    // ---- Phase C: nontemporal coalesced store ----
    const size_t obase = (size_t)ix * (NYv * NZv) + (size_t)iy0g * NZv + lane;
#pragma unroll
    for (int i = 0; i < 16; ++i) {
      const int c = i * 4 + wave;
      const float val = h_bits2f(tile_h[lane][c]);
      __builtin_nontemporal_store(val, &out[(size_t)c * NVOX + obase]);
    }
  }
}

// ---------------------------------------------------------------------------
// Fallback: direct channel-major sampling (no workspace).
// ---------------------------------------------------------------------------
__global__ __launch_bounds__(256) void sample_fallback(
    const float* __restrict__ feat,
    const float* __restrict__ points,
    const float* __restrict__ proj,
    float* __restrict__ out) {
  const int wave = threadIdx.x >> 6;
  const int lane = threadIdx.x & 63;
  const int n = blockIdx.x * 4 + wave;

  const float x = points[n * 3 + 0];
  const float y = points[n * 3 + 1];
  const float z = points[n * 3 + 2];

  float acc = 0.0f;
  int cnt = 0;

#pragma unroll
  for (int v = 0; v < NV; ++v) {
    const float* M = proj + v * 16;
    const float cx = M[0] * x + M[1] * y + M[2]  * z + M[3];
    const float cy = M[4] * x + M[5] * y + M[6]  * z + M[7];
    const float cz = M[8] * x + M[9] * y + M[10] * z + M[11];
    const float dz = (fabsf(cz) > 1e-6f) ? cz : 1e-6f;
    const float u  = cx / dz;
    const float vv = cy / dz;
    const bool valid = (cz > 0.0f) && (u > 0.0f) && (u < 1600.0f) &&
                       (vv > 0.0f) && (vv < 928.0f);
    if (!valid) continue;
    cnt++;
    const float px = u  / 1600.0f * 200.0f - 0.5f;
    const float py = vv / 928.0f  * 116.0f - 0.5f;
    const float fx0 = floorf(px);
    const float fy0 = floorf(py);
    const float wx1 = px - fx0;
    const float wy1 = py - fy0;
    const float wx0 = 1.0f - wx1;
    const float wy0 = 1.0f - wy1;
    const int ix0 = (int)fx0;
    const int iy0 = (int)fy0;
    const float w00 = wx0 * wy0, w10 = wx1 * wy0, w01 = wx0 * wy1, w11 = wx1 * wy1;
    const float* basev = feat + ((size_t)v * NC + lane) * PLANE;
    auto tap = [&](int xi, int yi, float w) {
      if (xi >= 0 && xi < WFv && yi >= 0 && yi < HFv)
        acc += w * basev[yi * WFv + xi];
    };
    tap(ix0,     iy0,     w00);
    tap(ix0 + 1, iy0,     w10);
    tap(ix0,     iy0 + 1, w01);
    tap(ix0 + 1, iy0 + 1, w11);
  }

  const float scale = (cnt > 0) ? (1.0f / (float)cnt) : 0.0f;
  const int iz  = n >> 14;
  const int rem = n & 16383;
  const int iy  = rem >> 7;
  const int ixx = rem & 127;
  out[(((size_t)lane * NXv + ixx) * NYv + iy) * NZv + iz] = acc * scale;
}

extern "C" void kernel_launch(void* const* d_in, const int* in_sizes, int n_in,
                              void* d_out, int out_size, void* d_ws, size_t ws_size,
                              hipStream_t stream) {
  const float* x_fov  = (const float*)d_in[0];  // [1,6,64,116,200] f32
  const float* points = (const float*)d_in[1];  // [131072,3] f32
  const float* proj   = (const float*)d_in[2];  // [6,4,4] f32
  float* out = (float*)d_out;                   // [1,64,128,128,8] f32

  if (ws_size >= FT_BYTES) {
    unsigned int* ft = (unsigned int*)d_ws;
    dim3 tgrid((PLANE + 63) / 64, NV);
    transpose_feat_bf16<<<tgrid, 256, 0, stream>>>(x_fov, ft);
    gather_fused<<<NXv * NYv / 8, 256, 0, stream>>>((const uint4*)ft, points, proj, out);
  } else {
    sample_fallback<<<NVOX / 4, 256, 0, stream>>>(x_fov, points, proj, out);
  }
}

// Round 6
// 131.646 us; speedup vs baseline: 1.2608x; 1.2608x over previous
//
#include <hip/hip_runtime.h>
#include <hip/hip_bf16.h>
#include <hip/hip_fp16.h>

// Problem constants
#define NXv 128
#define NYv 128
#define NZv 8
#define NVOX (NXv * NYv * NZv)   // 131072
#define NV 6
#define NC 64
#define HFv 116
#define WFv 200
#define PLANE (HFv * WFv)        // 23200

#define FT_BYTES ((size_t)NV * PLANE * NC * 2)   // 17,817,600 (bf16 channels-last)

// INSTRUMENTATION: K2 repeated idempotently so the gather dispatch stays above
// the ~44us fill cutoff in the top-5 rocprof table. K2new = (dur-83.9)/4.
#define K2_REP 4

// ---- helpers ---------------------------------------------------------------
__device__ inline unsigned int f2bf(float f) {   // f32 -> bf16 bits, RNE
  unsigned int x = __float_as_uint(f);
  unsigned int r = x + 0x7fffu + ((x >> 16) & 1u);
  return (r >> 16) & 0xffffu;
}
__device__ inline float bf_lo(unsigned int q) { return __uint_as_float(q << 16); }
__device__ inline float bf_hi(unsigned int q) { return __uint_as_float(q & 0xffff0000u); }

__device__ inline unsigned short f2h_bits(float f) {
  __half h = __float2half(f);
  return *reinterpret_cast<unsigned short*>(&h);
}
__device__ inline float h_bits2f(unsigned short u) {
  __half_raw r; r.x = u;
  __half h = *reinterpret_cast<__half*>(&r);
  return __half2float(h);
}

// ---------------------------------------------------------------------------
// K1: Transpose+convert [V][C][PLANE] f32 -> [V][PLANE][C] bf16 (packed).
// ---------------------------------------------------------------------------
__global__ __launch_bounds__(256) void transpose_feat_bf16(
    const float* __restrict__ in, unsigned int* __restrict__ out32) {
  __shared__ float tile[64][65];                 // [pixel][channel]
  const int v  = blockIdx.y;
  const int p0 = blockIdx.x * 64;
  const float* src = in + (size_t)v * NC * PLANE;
  unsigned int* dst = out32 + (size_t)v * PLANE * (NC / 2);
  const int t = threadIdx.x;

#pragma unroll
  for (int i = 0; i < 4; ++i) {
    const int idx = i * 256 + t;
    const int c  = idx >> 4;
    const int p4 = idx & 15;
    const int pp = p0 + p4 * 4;
    if (pp < PLANE) {                            // PLANE%4==0 -> full float4 ok
      const float4 f = *(const float4*)(src + (size_t)c * PLANE + pp);
      tile[p4 * 4 + 0][c] = f.x;
      tile[p4 * 4 + 1][c] = f.y;
      tile[p4 * 4 + 2][c] = f.z;
      tile[p4 * 4 + 3][c] = f.w;
    }
  }
  __syncthreads();

#pragma unroll
  for (int i = 0; i < 2; ++i) {
    const int idx = i * 256 + t;
    const int p   = idx >> 3;
    const int c8  = idx & 7;
    const int pp  = p0 + p;
    if (pp < PLANE) {
      uint4 w;
      w.x = f2bf(tile[p][c8 * 8 + 0]) | (f2bf(tile[p][c8 * 8 + 1]) << 16);
      w.y = f2bf(tile[p][c8 * 8 + 2]) | (f2bf(tile[p][c8 * 8 + 3]) << 16);
      w.z = f2bf(tile[p][c8 * 8 + 4]) | (f2bf(tile[p][c8 * 8 + 5]) << 16);
      w.w = f2bf(tile[p][c8 * 8 + 6]) | (f2bf(tile[p][c8 * 8 + 7]) << 16);
      *(uint4*)(dst + (size_t)pp * 32 + c8 * 4) = w;
    }
  }
}

// ---------------------------------------------------------------------------
// K2: Fused projection + gather + coalesced store.
// Round-6 restructure (occupancy was 35%: wave0-only Phase A left 3/4 waves
// idle at the barrier):
//  - Phase A runs on ALL 256 threads: thread (slot = t&63, vbase = t>>6)
//    handles views {vbase, vbase+4}. Valid recs go to a FIXED pdl_raw[64][6]
//    layout; validity via LDS atomicOr bitmask vmask[64]. No serial
//    compaction, no cntl/invl arrays.
//  - Phase B walks set bits of the mask (ctz), branchless; padded lanes gate
//    weights to 0. rec no longer packs the view -> cheap 16-bit p unpack:
//      rec.x = p00 | p10<<16 ; rec.y = p01 | p11<<16 ; rec.z/w = f16 weights.
//  - Accumulation order (increasing v) and all arithmetic identical to the
//    previous passing kernel -> bit-identical output.
// ---------------------------------------------------------------------------
__global__ __launch_bounds__(256, 4) void gather_fused(
    const uint4* __restrict__ feat4,    // [V*PLANE][8] uint4 (64 bf16 ch)
    const float* __restrict__ points,
    const float* __restrict__ proj,
    float* __restrict__ out) {
  __shared__ uint4 pdl_raw[64][NV];           // 6KB fixed (slot, view) recs
  __shared__ unsigned short tile_h[64][66];   // f16 staging, 8.4KB
  __shared__ unsigned int vmask[64];
  __shared__ float projl[96];

  // spatial swizzle: XCD (~bi&7) owns two 32ix x 32iy squares
  const int bi   = blockIdx.x;
  const int xcd  = bi & 7;
  const int r    = bi >> 3;
  const int tid  = xcd * 2 + (r >> 7);
  const int q    = r & 127;
  const int ix   = (tid & 3) * 32 + (q & 31);
  const int iyg  = (tid >> 2) * 4 + (q >> 5);
  const int iy0g = iyg * 8;

  const int t    = threadIdx.x;
  const int lane = t & 63;
  const int wave = t >> 6;

  if (t < 96) projl[t] = proj[t];

  for (int rep = 0; rep < K2_REP; ++rep) {
    if (t < 64) vmask[t] = 0u;
    __syncthreads();   // projl+clear visible; prev rep's B-reads of pdl_raw done

    // ---- Phase A: all 256 threads; (slot, view-pair) per thread ----
    {
      const int slot = t & 63;
      const int vb   = t >> 6;
      const int j    = slot >> 3;
      const int iz   = slot & 7;
      const int n    = iz * (NXv * NYv) + (iy0g + j) * NXv + ix;

      const float x = points[n * 3 + 0];
      const float y = points[n * 3 + 1];
      const float z = points[n * 3 + 2];

#pragma unroll
      for (int vo = 0; vo < 2; ++vo) {
        const int v = vb + vo * 4;
        if (v < NV) {
          const float* M = projl + v * 16;
          const float cx = M[0] * x + M[1] * y + M[2]  * z + M[3];
          const float cy = M[4] * x + M[5] * y + M[6]  * z + M[7];
          const float cz = M[8] * x + M[9] * y + M[10] * z + M[11];

          const float dz = (fabsf(cz) > 1e-6f) ? cz : 1e-6f;
          const float u  = cx / dz;
          const float vv = cy / dz;

          const bool valid = (cz > 0.0f) && (u > 0.0f) && (u < 1600.0f) &&
                             (vv > 0.0f) && (vv < 928.0f);
          if (valid) {
            const float px = u  / 1600.0f * 200.0f - 0.5f;
            const float py = vv / 928.0f  * 116.0f - 0.5f;
            const float fx0 = floorf(px);
            const float fy0 = floorf(py);
            const float wx1 = px - fx0;
            const float wy1 = py - fy0;
            const float wx0 = 1.0f - wx1;
            const float wy0 = 1.0f - wy1;
            const int ix0 = (int)fx0;
            const int iy0 = (int)fy0;

            // per-tap in-bounds masks (reference semantics)
            const bool bx0 = (ix0 >= 0) && (ix0 < WFv);
            const bool bx1 = (ix0 + 1 >= 0) && (ix0 + 1 < WFv);
            const bool by0 = (iy0 >= 0) && (iy0 < HFv);
            const bool by1 = (iy0 + 1 >= 0) && (iy0 + 1 < HFv);

            // per-tap independently clamped coords (reference semantics)
            const int xc0 = min(max(ix0, 0), WFv - 1);
            const int xc1 = min(max(ix0 + 1, 0), WFv - 1);
            const int yc0 = min(max(iy0, 0), HFv - 1);
            const int yc1 = min(max(iy0 + 1, 0), HFv - 1);
            const unsigned int p00 = (unsigned int)(yc0 * WFv + xc0);
            const unsigned int p10 = (unsigned int)(yc0 * WFv + xc1);
            const unsigned int p01 = (unsigned int)(yc1 * WFv + xc0);
            const unsigned int p11 = (unsigned int)(yc1 * WFv + xc1);

            uint4 rec;
            rec.x = p00 | (p10 << 16);
            rec.y = p01 | (p11 << 16);
            rec.z = (unsigned int)f2h_bits((bx0 && by0) ? wx0 * wy0 : 0.0f) |
                    ((unsigned int)f2h_bits((bx1 && by0) ? wx1 * wy0 : 0.0f) << 16);
            rec.w = (unsigned int)f2h_bits((bx0 && by1) ? wx0 * wy1 : 0.0f) |
                    ((unsigned int)f2h_bits((bx1 && by1) ? wx1 * wy1 : 0.0f) << 16);
            pdl_raw[slot][v] = rec;
            atomicOr(&vmask[slot], 1u << v);
          }
        }
      }
    }
    __syncthreads();

    // ---- Phase B: branchless taps via mask set-bit walk ----
    const int pg = lane >> 3;    // point within group of 8
    const int ch = lane & 7;     // uint4 chunk (8 channels)

#pragma unroll
    for (int it = 0; it < 2; ++it) {
      const int sl = wave * 16 + it * 8 + pg;
      unsigned int m = vmask[sl];
      const int mycnt = __popc(m);
      int km = mycnt;
      km = max(km, __shfl_xor(km, 8));
      km = max(km, __shfl_xor(km, 16));
      km = max(km, __shfl_xor(km, 32));   // wave-uniform max

      float acc[8];
#pragma unroll
      for (int j2 = 0; j2 < 8; ++j2) acc[j2] = 0.0f;

      for (int k = 0; k < km; ++k) {
        const bool live = (k < mycnt);
        const unsigned int msafe = live ? m : 1u;   // live => m != 0
        const int v = __builtin_ctz(msafe);
        m &= m - 1;

        const uint4 cur = pdl_raw[sl][v];
        const unsigned int p00 = cur.x & 0xffffu;
        const unsigned int p10 = cur.x >> 16;
        const unsigned int p01 = cur.y & 0xffffu;
        const unsigned int p11 = cur.y >> 16;
        const float w0 = live ? h_bits2f((unsigned short)(cur.z & 0xffffu)) : 0.0f;
        const float w1 = live ? h_bits2f((unsigned short)(cur.z >> 16))     : 0.0f;
        const float w2 = live ? h_bits2f((unsigned short)(cur.w & 0xffffu)) : 0.0f;
        const float w3 = live ? h_bits2f((unsigned short)(cur.w >> 16))     : 0.0f;

        const uint4* fb = feat4 + (size_t)v * (PLANE * 8) + ch;
        const uint4 q0 = fb[(size_t)p00 * 8];
        const uint4 q1 = fb[(size_t)p10 * 8];
        const uint4 q2 = fb[(size_t)p01 * 8];
        const uint4 q3 = fb[(size_t)p11 * 8];

        acc[0] = fmaf(w0, bf_lo(q0.x), acc[0]); acc[1] = fmaf(w0, bf_hi(q0.x), acc[1]);
        acc[2] = fmaf(w0, bf_lo(q0.y), acc[2]); acc[3] = fmaf(w0, bf_hi(q0.y), acc[3]);
        acc[4] = fmaf(w0, bf_lo(q0.z), acc[4]); acc[5] = fmaf(w0, bf_hi(q0.z), acc[5]);
        acc[6] = fmaf(w0, bf_lo(q0.w), acc[6]); acc[7] = fmaf(w0, bf_hi(q0.w), acc[7]);

        acc[0] = fmaf(w1, bf_lo(q1.x), acc[0]); acc[1] = fmaf(w1, bf_hi(q1.x), acc[1]);
        acc[2] = fmaf(w1, bf_lo(q1.y), acc[2]); acc[3] = fmaf(w1, bf_hi(q1.y), acc[3]);
        acc[4] = fmaf(w1, bf_lo(q1.z), acc[4]); acc[5] = fmaf(w1, bf_hi(q1.z), acc[5]);
        acc[6] = fmaf(w1, bf_lo(q1.w), acc[6]); acc[7] = fmaf(w1, bf_hi(q1.w), acc[7]);

        acc[0] = fmaf(w2, bf_lo(q2.x), acc[0]); acc[1] = fmaf(w2, bf_hi(q2.x), acc[1]);
        acc[2] = fmaf(w2, bf_lo(q2.y), acc[2]); acc[3] = fmaf(w2, bf_hi(q2.y), acc[3]);
        acc[4] = fmaf(w2, bf_lo(q2.z), acc[4]); acc[5] = fmaf(w2, bf_hi(q2.z), acc[5]);
        acc[6] = fmaf(w2, bf_lo(q2.w), acc[6]); acc[7] = fmaf(w2, bf_hi(q2.w), acc[7]);

        acc[0] = fmaf(w3, bf_lo(q3.x), acc[0]); acc[1] = fmaf(w3, bf_hi(q3.x), acc[1]);
        acc[2] = fmaf(w3, bf_lo(q3.y), acc[2]); acc[3] = fmaf(w3, bf_hi(q3.y), acc[3]);
        acc[4] = fmaf(w3, bf_lo(q3.z), acc[4]); acc[5] = fmaf(w3, bf_hi(q3.z), acc[5]);
        acc[6] = fmaf(w3, bf_lo(q3.w), acc[6]); acc[7] = fmaf(w3, bf_hi(q3.w), acc[7]);
      }

      const float inv = (mycnt > 0) ? 1.0f / (float)mycnt : 0.0f;
#pragma unroll
      for (int j2 = 0; j2 < 4; ++j2) {
        const unsigned int pk =
            (unsigned int)f2h_bits(acc[j2 * 2 + 0] * inv) |
            ((unsigned int)f2h_bits(acc[j2 * 2 + 1] * inv) << 16);
        *(unsigned int*)&tile_h[sl][ch * 8 + j2 * 2] = pk;
      }
    }

    __syncthreads();

    // ---- Phase C: nontemporal coalesced store ----
    const size_t obase = (size_t)ix * (NYv * NZv) + (size_t)iy0g * NZv + lane;
#pragma unroll
    for (int i = 0; i < 16; ++i) {
      const int c = i * 4 + wave;
      const float val = h_bits2f(tile_h[lane][c]);
      __builtin_nontemporal_store(val, &out[(size_t)c * NVOX + obase]);
    }
  }
}

// ---------------------------------------------------------------------------
// Fallback: direct channel-major sampling (no workspace).
// ---------------------------------------------------------------------------
__global__ __launch_bounds__(256) void sample_fallback(
    const float* __restrict__ feat,
    const float* __restrict__ points,
    const float* __restrict__ proj,
    float* __restrict__ out) {
  const int wave = threadIdx.x >> 6;
  const int lane = threadIdx.x & 63;
  const int n = blockIdx.x * 4 + wave;

  const float x = points[n * 3 + 0];
  const float y = points[n * 3 + 1];
  const float z = points[n * 3 + 2];

  float acc = 0.0f;
  int cnt = 0;

#pragma unroll
  for (int v = 0; v < NV; ++v) {
    const float* M = proj + v * 16;
    const float cx = M[0] * x + M[1] * y + M[2]  * z + M[3];
    const float cy = M[4] * x + M[5] * y + M[6]  * z + M[7];
    const float cz = M[8] * x + M[9] * y + M[10] * z + M[11];
    const float dz = (fabsf(cz) > 1e-6f) ? cz : 1e-6f;
    const float u  = cx / dz;
    const float vv = cy / dz;
    const bool valid = (cz > 0.0f) && (u > 0.0f) && (u < 1600.0f) &&
                       (vv > 0.0f) && (vv < 928.0f);
    if (!valid) continue;
    cnt++;
    const float px = u  / 1600.0f * 200.0f - 0.5f;
    const float py = vv / 928.0f  * 116.0f - 0.5f;
    const float fx0 = floorf(px);
    const float fy0 = floorf(py);
    const float wx1 = px - fx0;
    const float wy1 = py - fy0;
    const float wx0 = 1.0f - wx1;
    const float wy0 = 1.0f - wy1;
    const int ix0 = (int)fx0;
    const int iy0 = (int)fy0;
    const float w00 = wx0 * wy0, w10 = wx1 * wy0, w01 = wx0 * wy1, w11 = wx1 * wy1;
    const float* basev = feat + ((size_t)v * NC + lane) * PLANE;
    auto tap = [&](int xi, int yi, float w) {
      if (xi >= 0 && xi < WFv && yi >= 0 && yi < HFv)
        acc += w * basev[yi * WFv + xi];
    };
    tap(ix0,     iy0,     w00);
    tap(ix0 + 1, iy0,     w10);
    tap(ix0,     iy0 + 1, w01);
    tap(ix0 + 1, iy0 + 1, w11);
  }

  const float scale = (cnt > 0) ? (1.0f / (float)cnt) : 0.0f;
  const int iz  = n >> 14;
  const int rem = n & 16383;
  const int iy  = rem >> 7;
  const int ixx = rem & 127;
  out[(((size_t)lane * NXv + ixx) * NYv + iy) * NZv + iz] = acc * scale;
}

extern "C" void kernel_launch(void* const* d_in, const int* in_sizes, int n_in,
                              void* d_out, int out_size, void* d_ws, size_t ws_size,
                              hipStream_t stream) {
  const float* x_fov  = (const float*)d_in[0];  // [1,6,64,116,200] f32
  const float* points = (const float*)d_in[1];  // [131072,3] f32
  const float* proj   = (const float*)d_in[2];  // [6,4,4] f32
  float* out = (float*)d_out;                   // [1,64,128,128,8] f32

  if (ws_size >= FT_BYTES) {
    unsigned int* ft = (unsigned int*)d_ws;
    dim3 tgrid((PLANE + 63) / 64, NV);
    transpose_feat_bf16<<<tgrid, 256, 0, stream>>>(x_fov, ft);
    gather_fused<<<NXv * NYv / 8, 256, 0, stream>>>((const uint4*)ft, points, proj, out);
  } else {
    sample_fallback<<<NVOX / 4, 256, 0, stream>>>(x_fov, points, proj, out);
  }
}

// Round 7
// 99.118 us; speedup vs baseline: 1.6746x; 1.3282x over previous
//
#include <hip/hip_runtime.h>
#include <hip/hip_bf16.h>
#include <hip/hip_fp16.h>

// Problem constants
#define NXv 128
#define NYv 128
#define NZv 8
#define NVOX (NXv * NYv * NZv)   // 131072
#define NV 6
#define NC 64
#define HFv 116
#define WFv 200
#define PLANE (HFv * WFv)        // 23200

#define FT_BYTES ((size_t)NV * PLANE * NC * 2)   // 17,817,600 (bf16 channels-last)

// ---- helpers ---------------------------------------------------------------
typedef float v2f __attribute__((ext_vector_type(2)));

__device__ inline unsigned int f2bf(float f) {   // f32 -> bf16 bits, RNE
  unsigned int x = __float_as_uint(f);
  unsigned int r = x + 0x7fffu + ((x >> 16) & 1u);
  return (r >> 16) & 0xffffu;
}
__device__ inline float bf_lo(unsigned int q) { return __uint_as_float(q << 16); }
__device__ inline float bf_hi(unsigned int q) { return __uint_as_float(q & 0xffff0000u); }
__device__ inline v2f bfpair(unsigned int u) {   // packed bf16x2 -> float2
  v2f r;
  r.x = __uint_as_float(u << 16);
  r.y = __uint_as_float(u & 0xffff0000u);
  return r;
}

__device__ inline unsigned short f2h_bits(float f) {
  __half h = __float2half(f);
  return *reinterpret_cast<unsigned short*>(&h);
}
__device__ inline float h_bits2f(unsigned short u) {
  __half_raw r; r.x = u;
  __half h = *reinterpret_cast<__half*>(&r);
  return __half2float(h);
}

// ---------------------------------------------------------------------------
// K1: Transpose+convert [V][C][PLANE] f32 -> [V][PLANE][C] bf16 (packed).
// (At cold-BW floor: 53.4 MB compulsory ≈ 8.5 us.)
// ---------------------------------------------------------------------------
__global__ __launch_bounds__(256) void transpose_feat_bf16(
    const float* __restrict__ in, unsigned int* __restrict__ out32) {
  __shared__ float tile[64][65];                 // [pixel][channel]
  const int v  = blockIdx.y;
  const int p0 = blockIdx.x * 64;
  const float* src = in + (size_t)v * NC * PLANE;
  unsigned int* dst = out32 + (size_t)v * PLANE * (NC / 2);
  const int t = threadIdx.x;

#pragma unroll
  for (int i = 0; i < 4; ++i) {
    const int idx = i * 256 + t;
    const int c  = idx >> 4;
    const int p4 = idx & 15;
    const int pp = p0 + p4 * 4;
    if (pp < PLANE) {                            // PLANE%4==0 -> full float4 ok
      const float4 f = *(const float4*)(src + (size_t)c * PLANE + pp);
      tile[p4 * 4 + 0][c] = f.x;
      tile[p4 * 4 + 1][c] = f.y;
      tile[p4 * 4 + 2][c] = f.z;
      tile[p4 * 4 + 3][c] = f.w;
    }
  }
  __syncthreads();

#pragma unroll
  for (int i = 0; i < 2; ++i) {
    const int idx = i * 256 + t;
    const int p   = idx >> 3;
    const int c8  = idx & 7;
    const int pp  = p0 + p;
    if (pp < PLANE) {
      uint4 w;
      w.x = f2bf(tile[p][c8 * 8 + 0]) | (f2bf(tile[p][c8 * 8 + 1]) << 16);
      w.y = f2bf(tile[p][c8 * 8 + 2]) | (f2bf(tile[p][c8 * 8 + 3]) << 16);
      w.z = f2bf(tile[p][c8 * 8 + 4]) | (f2bf(tile[p][c8 * 8 + 5]) << 16);
      w.w = f2bf(tile[p][c8 * 8 + 6]) | (f2bf(tile[p][c8 * 8 + 7]) << 16);
      *(uint4*)(dst + (size_t)pp * 32 + c8 * 4) = w;
    }
  }
}

// ---------------------------------------------------------------------------
// K2: Fused projection + gather + coalesced store.
// Round-7 changes:
//  - Phase B regrouped: sl = pg*8 + wave*2 + it -> the 8 km-sharing points
//    are adjacent-y / same-z (coherent validity) instead of same-xy/all-z.
//  - Phase A zero-fills invalid (slot,view) recs; Phase B dead iterations
//    read the slot's first INVALID view (zeroed rec: w=0) -> no live-gating
//    cndmasks, dead loads are 4x same-address L1 hits.
//  - float2 accumulators via __builtin_elementwise_fma -> v_pk_fma_f32,
//    halving the FMA instruction count. Per-channel math/order identical.
// ---------------------------------------------------------------------------
__global__ __launch_bounds__(256, 4) void gather_fused(
    const uint4* __restrict__ feat4,    // [V*PLANE][8] uint4 (64 bf16 ch)
    const float* __restrict__ points,
    const float* __restrict__ proj,
    float* __restrict__ out) {
  __shared__ uint4 pdl_raw[64][NV];           // 6KB fixed (slot, view) recs
  __shared__ unsigned short tile_h[64][66];   // f16 staging, 8.4KB
  __shared__ unsigned int vmask[64];
  __shared__ float projl[96];

  // spatial swizzle: XCD (~bi&7) owns two 32ix x 32iy squares
  const int bi   = blockIdx.x;
  const int xcd  = bi & 7;
  const int r    = bi >> 3;
  const int tid  = xcd * 2 + (r >> 7);
  const int q    = r & 127;
  const int ix   = (tid & 3) * 32 + (q & 31);
  const int iyg  = (tid >> 2) * 4 + (q >> 5);
  const int iy0g = iyg * 8;

  const int t    = threadIdx.x;
  const int lane = t & 63;
  const int wave = t >> 6;

  if (t < 96) projl[t] = proj[t];
  if (t < 64) vmask[t] = 0u;
  __syncthreads();

  // ---- Phase A: all 256 threads; (slot, view-pair) per thread ----
  {
    const int slot = t & 63;
    const int vb   = t >> 6;
    const int j    = slot >> 3;
    const int iz   = slot & 7;
    const int n    = iz * (NXv * NYv) + (iy0g + j) * NXv + ix;

    const float x = points[n * 3 + 0];
    const float y = points[n * 3 + 1];
    const float z = points[n * 3 + 2];

#pragma unroll
    for (int vo = 0; vo < 2; ++vo) {
      const int v = vb + vo * 4;
      if (v < NV) {
        const float* M = projl + v * 16;
        const float cx = M[0] * x + M[1] * y + M[2]  * z + M[3];
        const float cy = M[4] * x + M[5] * y + M[6]  * z + M[7];
        const float cz = M[8] * x + M[9] * y + M[10] * z + M[11];

        const float dz = (fabsf(cz) > 1e-6f) ? cz : 1e-6f;
        const float u  = cx / dz;
        const float vv = cy / dz;

        const bool valid = (cz > 0.0f) && (u > 0.0f) && (u < 1600.0f) &&
                           (vv > 0.0f) && (vv < 928.0f);
        if (valid) {
          const float px = u  / 1600.0f * 200.0f - 0.5f;
          const float py = vv / 928.0f  * 116.0f - 0.5f;
          const float fx0 = floorf(px);
          const float fy0 = floorf(py);
          const float wx1 = px - fx0;
          const float wy1 = py - fy0;
          const float wx0 = 1.0f - wx1;
          const float wy0 = 1.0f - wy1;
          const int ix0 = (int)fx0;
          const int iy0 = (int)fy0;

          // per-tap in-bounds masks (reference semantics)
          const bool bx0 = (ix0 >= 0) && (ix0 < WFv);
          const bool bx1 = (ix0 + 1 >= 0) && (ix0 + 1 < WFv);
          const bool by0 = (iy0 >= 0) && (iy0 < HFv);
          const bool by1 = (iy0 + 1 >= 0) && (iy0 + 1 < HFv);

          // per-tap independently clamped coords (reference semantics)
          const int xc0 = min(max(ix0, 0), WFv - 1);
          const int xc1 = min(max(ix0 + 1, 0), WFv - 1);
          const int yc0 = min(max(iy0, 0), HFv - 1);
          const int yc1 = min(max(iy0 + 1, 0), HFv - 1);
          const unsigned int p00 = (unsigned int)(yc0 * WFv + xc0);
          const unsigned int p10 = (unsigned int)(yc0 * WFv + xc1);
          const unsigned int p01 = (unsigned int)(yc1 * WFv + xc0);
          const unsigned int p11 = (unsigned int)(yc1 * WFv + xc1);

          uint4 rec;
          rec.x = p00 | (p10 << 16);
          rec.y = p01 | (p11 << 16);
          rec.z = (unsigned int)f2h_bits((bx0 && by0) ? wx0 * wy0 : 0.0f) |
                  ((unsigned int)f2h_bits((bx1 && by0) ? wx1 * wy0 : 0.0f) << 16);
          rec.w = (unsigned int)f2h_bits((bx0 && by1) ? wx0 * wy1 : 0.0f) |
                  ((unsigned int)f2h_bits((bx1 && by1) ? wx1 * wy1 : 0.0f) << 16);
          pdl_raw[slot][v] = rec;
          atomicOr(&vmask[slot], 1u << v);
        } else {
          const uint4 zrec = {0u, 0u, 0u, 0u};
          pdl_raw[slot][v] = zrec;     // w=0, p=0 -> inert if ever read
        }
      }
    }
  }
  __syncthreads();

  // ---- Phase B: branchless taps via mask set-bit walk ----
  const int pg = lane >> 3;    // point within group of 8
  const int ch = lane & 7;     // uint4 chunk (8 channels)

#pragma unroll
  for (int it = 0; it < 2; ++it) {
    // adjacent-y / same-z grouping: j = pg varies, iz = wave*2+it fixed
    const int sl = pg * 8 + wave * 2 + it;
    const unsigned int m0 = vmask[sl];
    const int mycnt = __popc(m0);
    // first invalid view (zeroed rec) for dead iterations; exists iff mycnt<6
    const int vdead = min(__builtin_ctz(~m0), NV - 1);

    int km = mycnt;
    km = max(km, __shfl_xor(km, 8));
    km = max(km, __shfl_xor(km, 16));
    km = max(km, __shfl_xor(km, 32));   // wave-uniform max

    v2f acc2[4];
#pragma unroll
    for (int j2 = 0; j2 < 4; ++j2) acc2[j2] = (v2f){0.0f, 0.0f};

    unsigned int m = m0;
    for (int k = 0; k < km; ++k) {
      const bool live = (k < mycnt);
      const int v = live ? __builtin_ctz(m | 0x40u) : vdead;
      m &= m - 1;                       // m==0 stays 0

      const uint4 cur = pdl_raw[sl][v];
      const unsigned int p00 = cur.x & 0xffffu;
      const unsigned int p10 = cur.x >> 16;
      const unsigned int p01 = cur.y & 0xffffu;
      const unsigned int p11 = cur.y >> 16;
      const float w0 = h_bits2f((unsigned short)(cur.z & 0xffffu));
      const float w1 = h_bits2f((unsigned short)(cur.z >> 16));
      const float w2 = h_bits2f((unsigned short)(cur.w & 0xffffu));
      const float w3 = h_bits2f((unsigned short)(cur.w >> 16));

      const uint4* fb = feat4 + (size_t)v * (PLANE * 8) + ch;
      const uint4 q0 = fb[(size_t)p00 * 8];
      const uint4 q1 = fb[(size_t)p10 * 8];
      const uint4 q2 = fb[(size_t)p01 * 8];
      const uint4 q3 = fb[(size_t)p11 * 8];

      const v2f wv0 = (v2f){w0, w0};
      const v2f wv1 = (v2f){w1, w1};
      const v2f wv2 = (v2f){w2, w2};
      const v2f wv3 = (v2f){w3, w3};

      acc2[0] = __builtin_elementwise_fma(wv0, bfpair(q0.x), acc2[0]);
      acc2[1] = __builtin_elementwise_fma(wv0, bfpair(q0.y), acc2[1]);
      acc2[2] = __builtin_elementwise_fma(wv0, bfpair(q0.z), acc2[2]);
      acc2[3] = __builtin_elementwise_fma(wv0, bfpair(q0.w), acc2[3]);

      acc2[0] = __builtin_elementwise_fma(wv1, bfpair(q1.x), acc2[0]);
      acc2[1] = __builtin_elementwise_fma(wv1, bfpair(q1.y), acc2[1]);
      acc2[2] = __builtin_elementwise_fma(wv1, bfpair(q1.z), acc2[2]);
      acc2[3] = __builtin_elementwise_fma(wv1, bfpair(q1.w), acc2[3]);

      acc2[0] = __builtin_elementwise_fma(wv2, bfpair(q2.x), acc2[0]);
      acc2[1] = __builtin_elementwise_fma(wv2, bfpair(q2.y), acc2[1]);
      acc2[2] = __builtin_elementwise_fma(wv2, bfpair(q2.z), acc2[2]);
      acc2[3] = __builtin_elementwise_fma(wv2, bfpair(q2.w), acc2[3]);

      acc2[0] = __builtin_elementwise_fma(wv3, bfpair(q3.x), acc2[0]);
      acc2[1] = __builtin_elementwise_fma(wv3, bfpair(q3.y), acc2[1]);
      acc2[2] = __builtin_elementwise_fma(wv3, bfpair(q3.z), acc2[2]);
      acc2[3] = __builtin_elementwise_fma(wv3, bfpair(q3.w), acc2[3]);
    }

    const float inv = (mycnt > 0) ? 1.0f / (float)mycnt : 0.0f;
#pragma unroll
    for (int j2 = 0; j2 < 4; ++j2) {
      const unsigned int pk =
          (unsigned int)f2h_bits(acc2[j2].x * inv) |
          ((unsigned int)f2h_bits(acc2[j2].y * inv) << 16);
      *(unsigned int*)&tile_h[sl][ch * 8 + j2 * 2] = pk;
    }
  }

  __syncthreads();

  // ---- Phase C: nontemporal coalesced store ----
  const size_t obase = (size_t)ix * (NYv * NZv) + (size_t)iy0g * NZv + lane;
#pragma unroll
  for (int i = 0; i < 16; ++i) {
    const int c = i * 4 + wave;
    const float val = h_bits2f(tile_h[lane][c]);
    __builtin_nontemporal_store(val, &out[(size_t)c * NVOX + obase]);
  }
}

// ---------------------------------------------------------------------------
// Fallback: direct channel-major sampling (no workspace).
// ---------------------------------------------------------------------------
__global__ __launch_bounds__(256) void sample_fallback(
    const float* __restrict__ feat,
    const float* __restrict__ points,
    const float* __restrict__ proj,
    float* __restrict__ out) {
  const int wave = threadIdx.x >> 6;
  const int lane = threadIdx.x & 63;
  const int n = blockIdx.x * 4 + wave;

  const float x = points[n * 3 + 0];
  const float y = points[n * 3 + 1];
  const float z = points[n * 3 + 2];

  float acc = 0.0f;
  int cnt = 0;

#pragma unroll
  for (int v = 0; v < NV; ++v) {
    const float* M = proj + v * 16;
    const float cx = M[0] * x + M[1] * y + M[2]  * z + M[3];
    const float cy = M[4] * x + M[5] * y + M[6]  * z + M[7];
    const float cz = M[8] * x + M[9] * y + M[10] * z + M[11];
    const float dz = (fabsf(cz) > 1e-6f) ? cz : 1e-6f;
    const float u  = cx / dz;
    const float vv = cy / dz;
    const bool valid = (cz > 0.0f) && (u > 0.0f) && (u < 1600.0f) &&
                       (vv > 0.0f) && (vv < 928.0f);
    if (!valid) continue;
    cnt++;
    const float px = u  / 1600.0f * 200.0f - 0.5f;
    const float py = vv / 928.0f  * 116.0f - 0.5f;
    const float fx0 = floorf(px);
    const float fy0 = floorf(py);
    const float wx1 = px - fx0;
    const float wy1 = py - fy0;
    const float wx0 = 1.0f - wx1;
    const float wy0 = 1.0f - wy1;
    const int ix0 = (int)fx0;
    const int iy0 = (int)fy0;
    const float w00 = wx0 * wy0, w10 = wx1 * wy0, w01 = wx0 * wy1, w11 = wx1 * wy1;
    const float* basev = feat + ((size_t)v * NC + lane) * PLANE;
    auto tap = [&](int xi, int yi, float w) {
      if (xi >= 0 && xi < WFv && yi >= 0 && yi < HFv)
        acc += w * basev[yi * WFv + xi];
    };
    tap(ix0,     iy0,     w00);
    tap(ix0 + 1, iy0,     w10);
    tap(ix0,     iy0 + 1, w01);
    tap(ix0 + 1, iy0 + 1, w11);
  }

  const float scale = (cnt > 0) ? (1.0f / (float)cnt) : 0.0f;
  const int iz  = n >> 14;
  const int rem = n & 16383;
  const int iy  = rem >> 7;
  const int ixx = rem & 127;
  out[(((size_t)lane * NXv + ixx) * NYv + iy) * NZv + iz] = acc * scale;
}

extern "C" void kernel_launch(void* const* d_in, const int* in_sizes, int n_in,
                              void* d_out, int out_size, void* d_ws, size_t ws_size,
                              hipStream_t stream) {
  const float* x_fov  = (const float*)d_in[0];  // [1,6,64,116,200] f32
  const float* points = (const float*)d_in[1];  // [131072,3] f32
  const float* proj   = (const float*)d_in[2];  // [6,4,4] f32
  float* out = (float*)d_out;                   // [1,64,128,128,8] f32

  if (ws_size >= FT_BYTES) {
    unsigned int* ft = (unsigned int*)d_ws;
    dim3 tgrid((PLANE + 63) / 64, NV);
    transpose_feat_bf16<<<tgrid, 256, 0, stream>>>(x_fov, ft);
    gather_fused<<<NXv * NYv / 8, 256, 0, stream>>>((const uint4*)ft, points, proj, out);
  } else {
    sample_fallback<<<NVOX / 4, 256, 0, stream>>>(x_fov, points, proj, out);
  }
}

// Round 8
// 98.882 us; speedup vs baseline: 1.6786x; 1.0024x over previous
//
#include <hip/hip_runtime.h>
#include <hip/hip_bf16.h>
#include <hip/hip_fp16.h>

// Problem constants
#define NXv 128
#define NYv 128
#define NZv 8
#define NVOX (NXv * NYv * NZv)   // 131072
#define NV 6
#define NC 64
#define HFv 116
#define WFv 200
#define PLANE (HFv * WFv)        // 23200

#define FT_BYTES ((size_t)NV * PLANE * NC * 2)   // 17,817,600 (bf16 channels-last)

// ---- helpers ---------------------------------------------------------------
typedef float v2f __attribute__((ext_vector_type(2)));

__device__ inline unsigned int f2bf(float f) {   // f32 -> bf16 bits, RNE
  unsigned int x = __float_as_uint(f);
  unsigned int r = x + 0x7fffu + ((x >> 16) & 1u);
  return (r >> 16) & 0xffffu;
}
__device__ inline v2f bfpair(unsigned int u) {   // packed bf16x2 -> float2
  v2f r;
  r.x = __uint_as_float(u << 16);
  r.y = __uint_as_float(u & 0xffff0000u);
  return r;
}

__device__ inline unsigned short f2h_bits(float f) {
  __half h = __float2half(f);
  return *reinterpret_cast<unsigned short*>(&h);
}
__device__ inline float h_bits2f(unsigned short u) {
  __half_raw r; r.x = u;
  __half h = *reinterpret_cast<__half*>(&r);
  return __half2float(h);
}

// ---------------------------------------------------------------------------
// K1: Transpose+convert [V][C][PLANE] f32 -> [V][PLANE][C] bf16 (packed).
// (At cold-BW floor: 53.4 MB compulsory ≈ 8.5 us.)
// ---------------------------------------------------------------------------
__global__ __launch_bounds__(256) void transpose_feat_bf16(
    const float* __restrict__ in, unsigned int* __restrict__ out32) {
  __shared__ float tile[64][65];                 // [pixel][channel]
  const int v  = blockIdx.y;
  const int p0 = blockIdx.x * 64;
  const float* src = in + (size_t)v * NC * PLANE;
  unsigned int* dst = out32 + (size_t)v * PLANE * (NC / 2);
  const int t = threadIdx.x;

#pragma unroll
  for (int i = 0; i < 4; ++i) {
    const int idx = i * 256 + t;
    const int c  = idx >> 4;
    const int p4 = idx & 15;
    const int pp = p0 + p4 * 4;
    if (pp < PLANE) {                            // PLANE%4==0 -> full float4 ok
      const float4 f = *(const float4*)(src + (size_t)c * PLANE + pp);
      tile[p4 * 4 + 0][c] = f.x;
      tile[p4 * 4 + 1][c] = f.y;
      tile[p4 * 4 + 2][c] = f.z;
      tile[p4 * 4 + 3][c] = f.w;
    }
  }
  __syncthreads();

#pragma unroll
  for (int i = 0; i < 2; ++i) {
    const int idx = i * 256 + t;
    const int p   = idx >> 3;
    const int c8  = idx & 7;
    const int pp  = p0 + p;
    if (pp < PLANE) {
      uint4 w;
      w.x = f2bf(tile[p][c8 * 8 + 0]) | (f2bf(tile[p][c8 * 8 + 1]) << 16);
      w.y = f2bf(tile[p][c8 * 8 + 2]) | (f2bf(tile[p][c8 * 8 + 3]) << 16);
      w.z = f2bf(tile[p][c8 * 8 + 4]) | (f2bf(tile[p][c8 * 8 + 5]) << 16);
      w.w = f2bf(tile[p][c8 * 8 + 6]) | (f2bf(tile[p][c8 * 8 + 7]) << 16);
      *(uint4*)(dst + (size_t)pp * 32 + c8 * 4) = w;
    }
  }
}

// ---------------------------------------------------------------------------
// K2: Fused projection + gather + coalesced store.
// Round-8 changes (issue-diet; VALUBusy was 57% of warm time):
//  - Phase B TAP-SPLIT: 64 lanes = 4 points x 8 ch-chunks x 2 tap-halves.
//    half 0 handles taps (p00,p10), half 1 handles (p01,p11): per k per lane
//    2 loads + 8 pk-FMA instead of 4 loads + 16 pk-FMA. One shfl_xor(.,1)+add
//    merges halves after the k-loop. km now shared by 4 same-z adjacent-j
//    points (tighter than 8).
//  - Weights stored as f32 float4 in LDS (no f16 encode/decode on the k path).
//  - Phase A / Phase C / grids unchanged.
// ---------------------------------------------------------------------------
__global__ __launch_bounds__(256, 4) void gather_fused(
    const uint4* __restrict__ feat4,    // [V*PLANE][8] uint4 (64 bf16 ch)
    const float* __restrict__ points,
    const float* __restrict__ proj,
    float* __restrict__ out) {
  __shared__ uint2  pdl_pix[64][NV];          // 3KB  (p00|p10<<16, p01|p11<<16)
  __shared__ float4 pdl_w[64][NV];            // 6KB  (w00,w10,w01,w11) f32
  __shared__ unsigned short tile_h[64][66];   // 8.4KB f16 staging
  __shared__ unsigned int vmask[64];
  __shared__ float projl[96];

  // spatial swizzle: XCD (~bi&7) owns two 32ix x 32iy squares
  const int bi   = blockIdx.x;
  const int xcd  = bi & 7;
  const int r    = bi >> 3;
  const int tid  = xcd * 2 + (r >> 7);
  const int q    = r & 127;
  const int ix   = (tid & 3) * 32 + (q & 31);
  const int iyg  = (tid >> 2) * 4 + (q >> 5);
  const int iy0g = iyg * 8;

  const int t    = threadIdx.x;
  const int lane = t & 63;
  const int wave = t >> 6;

  if (t < 96) projl[t] = proj[t];
  if (t < 64) vmask[t] = 0u;
  __syncthreads();

  // ---- Phase A: all 256 threads; (slot, view-pair) per thread ----
  {
    const int slot = t & 63;
    const int vb   = t >> 6;
    const int j    = slot >> 3;
    const int iz   = slot & 7;
    const int n    = iz * (NXv * NYv) + (iy0g + j) * NXv + ix;

    const float x = points[n * 3 + 0];
    const float y = points[n * 3 + 1];
    const float z = points[n * 3 + 2];

#pragma unroll
    for (int vo = 0; vo < 2; ++vo) {
      const int v = vb + vo * 4;
      if (v < NV) {
        const float* M = projl + v * 16;
        const float cx = M[0] * x + M[1] * y + M[2]  * z + M[3];
        const float cy = M[4] * x + M[5] * y + M[6]  * z + M[7];
        const float cz = M[8] * x + M[9] * y + M[10] * z + M[11];

        const float dz = (fabsf(cz) > 1e-6f) ? cz : 1e-6f;
        const float u  = cx / dz;
        const float vv = cy / dz;

        const bool valid = (cz > 0.0f) && (u > 0.0f) && (u < 1600.0f) &&
                           (vv > 0.0f) && (vv < 928.0f);
        if (valid) {
          const float px = u  / 1600.0f * 200.0f - 0.5f;
          const float py = vv / 928.0f  * 116.0f - 0.5f;
          const float fx0 = floorf(px);
          const float fy0 = floorf(py);
          const float wx1 = px - fx0;
          const float wy1 = py - fy0;
          const float wx0 = 1.0f - wx1;
          const float wy0 = 1.0f - wy1;
          const int ix0 = (int)fx0;
          const int iy0 = (int)fy0;

          // per-tap in-bounds masks (reference semantics)
          const bool bx0 = (ix0 >= 0) && (ix0 < WFv);
          const bool bx1 = (ix0 + 1 >= 0) && (ix0 + 1 < WFv);
          const bool by0 = (iy0 >= 0) && (iy0 < HFv);
          const bool by1 = (iy0 + 1 >= 0) && (iy0 + 1 < HFv);

          // per-tap independently clamped coords (reference semantics)
          const int xc0 = min(max(ix0, 0), WFv - 1);
          const int xc1 = min(max(ix0 + 1, 0), WFv - 1);
          const int yc0 = min(max(iy0, 0), HFv - 1);
          const int yc1 = min(max(iy0 + 1, 0), HFv - 1);
          const unsigned int p00 = (unsigned int)(yc0 * WFv + xc0);
          const unsigned int p10 = (unsigned int)(yc0 * WFv + xc1);
          const unsigned int p01 = (unsigned int)(yc1 * WFv + xc0);
          const unsigned int p11 = (unsigned int)(yc1 * WFv + xc1);

          uint2 pix;
          pix.x = p00 | (p10 << 16);
          pix.y = p01 | (p11 << 16);
          float4 wv;
          wv.x = (bx0 && by0) ? wx0 * wy0 : 0.0f;
          wv.y = (bx1 && by0) ? wx1 * wy0 : 0.0f;
          wv.z = (bx0 && by1) ? wx0 * wy1 : 0.0f;
          wv.w = (bx1 && by1) ? wx1 * wy1 : 0.0f;
          pdl_pix[slot][v] = pix;
          pdl_w[slot][v]   = wv;
          atomicOr(&vmask[slot], 1u << v);
        } else {
          pdl_pix[slot][v] = (uint2){0u, 0u};
          pdl_w[slot][v]   = (float4){0.0f, 0.0f, 0.0f, 0.0f};
        }
      }
    }
  }
  __syncthreads();

  // ---- Phase B: tap-split branchless gather ----
  // lane = pg2(2b) | ch(3b) | half(1b):  4 points x 8 ch-chunks x 2 halves
  const int pg2  = lane >> 4;        // point within group of 4
  const int ch   = (lane >> 1) & 7;  // uint4 chunk (8 channels)
  const int half = lane & 1;         // 0: taps (p00,p10)  1: taps (p01,p11)

#pragma unroll
  for (int i = 0; i < 4; ++i) {
    const int gi = wave * 4 + i;     // 0..15
    const int jg = gi >> 3;          // 0..1
    const int iz = gi & 7;
    const int sl = (jg * 4 + pg2) * 8 + iz;   // same-z, adjacent-j group of 4

    const unsigned int m0 = vmask[sl];
    const int mycnt = __popc(m0);
    const int vdead = min(__builtin_ctz(~m0), NV - 1);

    int km = mycnt;
    km = max(km, __shfl_xor(km, 16));
    km = max(km, __shfl_xor(km, 32));   // wave-uniform max over the 4 points

    v2f acc2[4];
#pragma unroll
    for (int j2 = 0; j2 < 4; ++j2) acc2[j2] = (v2f){0.0f, 0.0f};

    unsigned int m = m0;
    for (int k = 0; k < km; ++k) {
      const bool live = (k < mycnt);
      const int v = live ? __builtin_ctz(m | 0x40u) : vdead;
      m &= m - 1;                       // m==0 stays 0

      const uint2 pix = pdl_pix[sl][v];
      const unsigned int ui = half ? pix.y : pix.x;
      const unsigned int pa = ui & 0xffffu;
      const unsigned int pb = ui >> 16;
      const v2f wp = *((const v2f*)&pdl_w[sl][v] + half);  // (wa, wb)

      const uint4* fb = feat4 + (size_t)v * (PLANE * 8) + ch;
      const uint4 qa = fb[(size_t)pa * 8];
      const uint4 qb = fb[(size_t)pb * 8];

      const v2f wva = (v2f){wp.x, wp.x};
      const v2f wvb = (v2f){wp.y, wp.y};

      acc2[0] = __builtin_elementwise_fma(wva, bfpair(qa.x), acc2[0]);
      acc2[1] = __builtin_elementwise_fma(wva, bfpair(qa.y), acc2[1]);
      acc2[2] = __builtin_elementwise_fma(wva, bfpair(qa.z), acc2[2]);
      acc2[3] = __builtin_elementwise_fma(wva, bfpair(qa.w), acc2[3]);

      acc2[0] = __builtin_elementwise_fma(wvb, bfpair(qb.x), acc2[0]);
      acc2[1] = __builtin_elementwise_fma(wvb, bfpair(qb.y), acc2[1]);
      acc2[2] = __builtin_elementwise_fma(wvb, bfpair(qb.z), acc2[2]);
      acc2[3] = __builtin_elementwise_fma(wvb, bfpair(qb.w), acc2[3]);
    }

    // merge tap-halves: partner lane = lane ^ 1
#pragma unroll
    for (int j2 = 0; j2 < 4; ++j2) {
      acc2[j2].x += __shfl_xor(acc2[j2].x, 1);
      acc2[j2].y += __shfl_xor(acc2[j2].y, 1);
    }

    if (half == 0) {
      const float inv = (mycnt > 0) ? 1.0f / (float)mycnt : 0.0f;
#pragma unroll
      for (int j2 = 0; j2 < 4; ++j2) {
        const unsigned int pk =
            (unsigned int)f2h_bits(acc2[j2].x * inv) |
            ((unsigned int)f2h_bits(acc2[j2].y * inv) << 16);
        *(unsigned int*)&tile_h[sl][ch * 8 + j2 * 2] = pk;
      }
    }
  }

  __syncthreads();

  // ---- Phase C: nontemporal coalesced store ----
  const size_t obase = (size_t)ix * (NYv * NZv) + (size_t)iy0g * NZv + lane;
#pragma unroll
  for (int i = 0; i < 16; ++i) {
    const int c = i * 4 + wave;
    const float val = h_bits2f(tile_h[lane][c]);
    __builtin_nontemporal_store(val, &out[(size_t)c * NVOX + obase]);
  }
}

// ---------------------------------------------------------------------------
// Fallback: direct channel-major sampling (no workspace).
// ---------------------------------------------------------------------------
__global__ __launch_bounds__(256) void sample_fallback(
    const float* __restrict__ feat,
    const float* __restrict__ points,
    const float* __restrict__ proj,
    float* __restrict__ out) {
  const int wave = threadIdx.x >> 6;
  const int lane = threadIdx.x & 63;
  const int n = blockIdx.x * 4 + wave;

  const float x = points[n * 3 + 0];
  const float y = points[n * 3 + 1];
  const float z = points[n * 3 + 2];

  float acc = 0.0f;
  int cnt = 0;

#pragma unroll
  for (int v = 0; v < NV; ++v) {
    const float* M = proj + v * 16;
    const float cx = M[0] * x + M[1] * y + M[2]  * z + M[3];
    const float cy = M[4] * x + M[5] * y + M[6]  * z + M[7];
    const float cz = M[8] * x + M[9] * y + M[10] * z + M[11];
    const float dz = (fabsf(cz) > 1e-6f) ? cz : 1e-6f;
    const float u  = cx / dz;
    const float vv = cy / dz;
    const bool valid = (cz > 0.0f) && (u > 0.0f) && (u < 1600.0f) &&
                       (vv > 0.0f) && (vv < 928.0f);
    if (!valid) continue;
    cnt++;
    const float px = u  / 1600.0f * 200.0f - 0.5f;
    const float py = vv / 928.0f  * 116.0f - 0.5f;
    const float fx0 = floorf(px);
    const float fy0 = floorf(py);
    const float wx1 = px - fx0;
    const float wy1 = py - fy0;
    const float wx0 = 1.0f - wx1;
    const float wy0 = 1.0f - wy1;
    const int ix0 = (int)fx0;
    const int iy0 = (int)fy0;
    const float w00 = wx0 * wy0, w10 = wx1 * wy0, w01 = wx0 * wy1, w11 = wx1 * wy1;
    const float* basev = feat + ((size_t)v * NC + lane) * PLANE;
    auto tap = [&](int xi, int yi, float w) {
      if (xi >= 0 && xi < WFv && yi >= 0 && yi < HFv)
        acc += w * basev[yi * WFv + xi];
    };
    tap(ix0,     iy0,     w00);
    tap(ix0 + 1, iy0,     w10);
    tap(ix0,     iy0 + 1, w01);
    tap(ix0 + 1, iy0 + 1, w11);
  }

  const float scale = (cnt > 0) ? (1.0f / (float)cnt) : 0.0f;
  const int iz  = n >> 14;
  const int rem = n & 16383;
  const int iy  = rem >> 7;
  const int ixx = rem & 127;
  out[(((size_t)lane * NXv + ixx) * NYv + iy) * NZv + iz] = acc * scale;
}

extern "C" void kernel_launch(void* const* d_in, const int* in_sizes, int n_in,
                              void* d_out, int out_size, void* d_ws, size_t ws_size,
                              hipStream_t stream) {
  const float* x_fov  = (const float*)d_in[0];  // [1,6,64,116,200] f32
  const float* points = (const float*)d_in[1];  // [131072,3] f32
  const float* proj   = (const float*)d_in[2];  // [6,4,4] f32
  float* out = (float*)d_out;                   // [1,64,128,128,8] f32

  if (ws_size >= FT_BYTES) {
    unsigned int* ft = (unsigned int*)d_ws;
    dim3 tgrid((PLANE + 63) / 64, NV);
    transpose_feat_bf16<<<tgrid, 256, 0, stream>>>(x_fov, ft);
    gather_fused<<<NXv * NYv / 8, 256, 0, stream>>>((const uint4*)ft, points, proj, out);
  } else {
    sample_fallback<<<NVOX / 4, 256, 0, stream>>>(x_fov, points, proj, out);
  }
}